// Round 18
// baseline (564.357 us; speedup 1.0000x reference)
//
#include <hip/hip_runtime.h>

// AutoregressiveForecaster R18: R16 base + split MFMA chain + merged
// blend/prologue interval + retuned stagger.
// 2-layer LSTM(H=64) + MLP head, 20 steps, 24-window, B=8192.
//
//  - R9/R16 structure: 512 blocks x 256 threads (4 waves), one 16-batch
//    M-tile/block, 2 blocks/CU, pipelined L1(t)+L0(t+1), fused-7 gates,
//    log2e-prescaled weights (2x g-gate) in VGPRs, phase stagger + setprio.
//  - acc1 chain split 2+2: u=(bias,a1lo,a1hi), v=(0,a2lo,a2hi), acc=u+v.
//    Critical path 4 MFMA -> 2 MFMA + add (~-60cy/interval).
//  - blend/win-write merged into next step's prologue interval (27->26
//    barriers/step): pm synced by MLP barrier; win slot (s-1)%24 first read
//    at iter 22; prologue writes only h1s[0].
//  - stagger = 1230 ticks (~half the 2460cy measured interval).

typedef _Float16 f16x8 __attribute__((ext_vector_type(8)));
typedef float f32x4 __attribute__((ext_vector_type(4)));

#define NBLK 512
#define NTHR 256
#define SRB  144   // h row stride bytes

__device__ __forceinline__ float rcp_(float x) { return __builtin_amdgcn_rcpf(x); }
__device__ __forceinline__ float exp2_(float x) { return __builtin_amdgcn_exp2f(x); }
__device__ __forceinline__ f32x4 mfma16(uint4 a, uint4 b, f32x4 c) {
  return __builtin_amdgcn_mfma_f32_16x16x32_f16(
      __builtin_bit_cast(f16x8, a), __builtin_bit_cast(f16x8, b), c, 0, 0, 0);
}
__device__ __forceinline__ uint4 pack8s(const float* p, float s) {
  union { uint4 u; _Float16 h[8]; } r;
  #pragma unroll
  for (int i = 0; i < 8; ++i) r.h[i] = (_Float16)(p[i] * s);
  return r.u;
}
// fused LSTM gate update; pre-activations pre-scaled by log2e (2x for g-gate).
__device__ __forceinline__ float gatestep(float aI, float aF, float aG, float aO,
                                          float& cst) {
  float xx = exp2_(-aI), xf = exp2_(-aF), yy = exp2_(-aG), xo = exp2_(-aO);
  float P = (1.0f + xx) * (1.0f + yy);
  float Q = 1.0f + xf;
  float N = fmaf(cst, P, (1.0f - yy) * Q);   // c*P + (1-yy)*Q
  float cv = N * rcp_(P * Q);
  cst = cv;
  float z = exp2_(-2.88539008178f * cv);
  return (1.0f - z) * rcp_((1.0f + xo) * (1.0f + z));
}

__global__ __launch_bounds__(NTHR, 2) void lstm_forecast(
    const float* __restrict__ x,
    const float* __restrict__ Wih0, const float* __restrict__ Whh0,
    const float* __restrict__ bih0, const float* __restrict__ bhh0,
    const float* __restrict__ Wih1, const float* __restrict__ Whh1,
    const float* __restrict__ bih1, const float* __restrict__ bhh1,
    const float* __restrict__ W1,   const float* __restrict__ b1,
    const float* __restrict__ W2,   const float* __restrict__ b2,
    const float* __restrict__ damping, const int* __restrict__ stepsPtr,
    float* __restrict__ out)
{
  __shared__ __align__(16) char h1s[2][16 * SRB];
  __shared__ __align__(16) char h2s[2][16 * SRB];
  __shared__ __align__(16) float win[24 * 16];
  __shared__ __align__(16) float pm[2][16];

  const int tid  = threadIdx.x;
  const int wave = tid >> 6;
  const int lane = tid & 63;
  const int cc   = lane & 15;
  const int hi   = lane >> 4;
  const int b0g  = blockIdx.x * 16;
  const float L2E = 1.44269504089f;

  // ---- weight B-fragments into VGPRs (pre-scaled; gt: 0=i,1=f,2=g,3=o) ----
  uint4 wB0[4][2], wB1[4][2], wB2[4][2];
  float bias0v[4], wih0v[4];
  f32x4 bi1[4];
  #pragma unroll
  for (int gt = 0; gt < 4; ++gt) {
    float sc = (gt == 2) ? 2.0f * L2E : L2E;
    int row = (wave + 4 * gt) * 16 + cc;
    #pragma unroll
    for (int f = 0; f < 2; ++f) {
      int col = f * 32 + hi * 8;
      wB0[gt][f] = pack8s(Whh0 + row * 64 + col, sc);
      wB1[gt][f] = pack8s(Wih1 + row * 64 + col, sc);
      wB2[gt][f] = pack8s(Whh1 + row * 64 + col, sc);
    }
    bias0v[gt] = (bih0[row] + bhh0[row]) * sc;
    wih0v[gt]  = Wih0[row] * sc;
    float b1c  = (bih1[row] + bhh1[row]) * sc;
    #pragma unroll
    for (int r = 0; r < 4; ++r) bi1[gt][r] = b1c;
  }
  // MLP fragments (waves 0,1 use them; 2,3 load duplicates harmlessly)
  uint4 wM[2];
  {
    int row = (wave & 1) * 16 + cc;
    wM[0] = pack8s(W1 + row * 64 + hi * 8, 1.0f);
    wM[1] = pack8s(W1 + row * 64 + 32 + hi * 8, 1.0f);
  }
  const float w2v  = W2[(wave & 1) * 16 + cc];
  const float b1vv = b1[(wave & 1) * 16 + cc];
  const float alpha  = rcp_(1.0f + exp2_(-L2E * damping[0]));
  const int   nsteps = stepsPtr[0];
  const float b2v    = b2[0];

  // window init: win[t*16+b] = x[(b0g+b)*24 + t]
  for (int e = tid; e < 384; e += NTHR) {
    int b = e & 15, t = e >> 4;
    win[t * 16 + b] = x[(b0g + b) * 24 + t];
  }
  __syncthreads();

  // ---- one-time phase stagger (R16-verified lever; ~half interval) ----
  if (blockIdx.x & 1) {
    unsigned long long t0 = __builtin_amdgcn_s_memtime();
    while (__builtin_amdgcn_s_memtime() - t0 < 1230ull) { }
  }

  const int offA = cc * SRB + hi * 16;           // A-frag byte offset
  const int offS = (wave * 16 + cc) * 2;         // elementwise store offset
  const f32x4 z4 = {0.0f, 0.0f, 0.0f, 0.0f};
  float prevp = 0.0f;

  for (int s = 0; s < nsteps; ++s) {
    float c1[4] = {0, 0, 0, 0}, c2s[4] = {0, 0, 0, 0};

    // ---- merged interval: blend/write pred(s-1) + prologue L0(0) ----
    if (s > 0 && wave == 0 && lane < 16) {
      float y = pm[0][lane] + pm[1][lane] + b2v;
      float pd = (s == 1) ? y : fmaf(y, 1.0f - alpha, prevp * (alpha * 0.5f));
      prevp = pd;
      int slot = (s - 1) % 24;
      win[slot * 16 + lane] = pd;      // first read at iter 22 of this step
      out[(long)(b0g + lane) * nsteps + (s - 1)] = pd;
    }
    {
      float4 xw = *(const float4*)&win[(s % 24) * 16 + hi * 4];
      float xa[4] = {xw.x, xw.y, xw.z, xw.w};
      #pragma unroll
      for (int r = 0; r < 4; ++r) {
        float hv = gatestep(fmaf(xa[r], wih0v[0], bias0v[0]),
                            fmaf(xa[r], wih0v[1], bias0v[1]),
                            fmaf(xa[r], wih0v[2], bias0v[2]),
                            fmaf(xa[r], wih0v[3], bias0v[3]), c1[r]);
        *(_Float16*)(h1s[0] + (hi * 4 + r) * SRB + offS) = (_Float16)hv;
      }
    }
    __syncthreads();
    uint4 a1lo = *(const uint4*)(h1s[0] + offA);
    uint4 a1hi = *(const uint4*)(h1s[0] + offA + 64);
    uint4 a2lo = make_uint4(0, 0, 0, 0), a2hi = make_uint4(0, 0, 0, 0);

    // ---- main pipelined loop: iter t computes L1(t) and L0(t+1) ----
    for (int t = 0; t < 23; ++t) {
      int pb = (t + 1) & 1;
      int ph = s + t + 1; if (ph >= 24) ph -= 24;
      float4 xw = *(const float4*)&win[ph * 16 + hi * 4];
      float xa[4] = {xw.x, xw.y, xw.z, xw.w};

      f32x4 acc1[4], acc0[4];
      #pragma unroll
      for (int gt = 0; gt < 4; ++gt) {
        f32x4 u = mfma16(a1lo, wB1[gt][0], bi1[gt]);
        u = mfma16(a1hi, wB1[gt][1], u);
        f32x4 v = mfma16(a2lo, wB2[gt][0], z4);
        v = mfma16(a2hi, wB2[gt][1], v);
        acc1[gt] = u + v;                  // 2+2 split: halves MFMA chain depth
      }
      #pragma unroll
      for (int gt = 0; gt < 4; ++gt) {
        f32x4 ai;
        #pragma unroll
        for (int r = 0; r < 4; ++r) ai[r] = fmaf(xa[r], wih0v[gt], bias0v[gt]);
        f32x4 tv = mfma16(a1lo, wB0[gt][0], ai);
        acc0[gt] = mfma16(a1hi, wB0[gt][1], tv);
      }

      __builtin_amdgcn_s_setprio(1);
      char* h2d = h2s[pb];
      char* h1d = h1s[pb];
      #pragma unroll
      for (int r = 0; r < 4; ++r) {
        float hv = gatestep(acc1[0][r], acc1[1][r], acc1[2][r], acc1[3][r], c2s[r]);
        *(_Float16*)(h2d + (hi * 4 + r) * SRB + offS) = (_Float16)hv;
      }
      #pragma unroll
      for (int r = 0; r < 4; ++r) {
        float hv = gatestep(acc0[0][r], acc0[1][r], acc0[2][r], acc0[3][r], c1[r]);
        *(_Float16*)(h1d + (hi * 4 + r) * SRB + offS) = (_Float16)hv;
      }
      __builtin_amdgcn_s_setprio(0);
      __syncthreads();
      a1lo = *(const uint4*)(h1s[pb] + offA);
      a1hi = *(const uint4*)(h1s[pb] + offA + 64);
      a2lo = *(const uint4*)(h2s[pb] + offA);
      a2hi = *(const uint4*)(h2s[pb] + offA + 64);
    } // t

    // ---- epilogue: L1(23) -> h2s[0] ----
    {
      f32x4 acc1[4];
      #pragma unroll
      for (int gt = 0; gt < 4; ++gt) {
        f32x4 u = mfma16(a1lo, wB1[gt][0], bi1[gt]);
        u = mfma16(a1hi, wB1[gt][1], u);
        f32x4 v = mfma16(a2lo, wB2[gt][0], z4);
        v = mfma16(a2hi, wB2[gt][1], v);
        acc1[gt] = u + v;
      }
      __builtin_amdgcn_s_setprio(1);
      #pragma unroll
      for (int r = 0; r < 4; ++r) {
        float cv = c2s[r];
        float hv = gatestep(acc1[0][r], acc1[1][r], acc1[2][r], acc1[3][r], cv);
        *(_Float16*)(h2s[0] + (hi * 4 + r) * SRB + offS) = (_Float16)hv;
      }
      __builtin_amdgcn_s_setprio(0);
    }
    __syncthreads();

    // ---- MLP head on h2(23) (waves 0,1) ----
    if (wave < 2) {
      uint4 hflo = *(const uint4*)(h2s[0] + offA);
      uint4 hfhi = *(const uint4*)(h2s[0] + offA + 64);
      f32x4 am;
      #pragma unroll
      for (int r = 0; r < 4; ++r) am[r] = b1vv;
      am = mfma16(hflo, wM[0], am);
      am = mfma16(hfhi, wM[1], am);
      float yp[4];
      #pragma unroll
      for (int r = 0; r < 4; ++r) yp[r] = fmaxf(am[r], 0.0f) * w2v;
      #pragma unroll
      for (int mask = 1; mask <= 8; mask <<= 1) {
        #pragma unroll
        for (int r = 0; r < 4; ++r) yp[r] += __shfl_xor(yp[r], mask);
      }
      if (cc == 0) {
        #pragma unroll
        for (int r = 0; r < 4; ++r) pm[wave][hi * 4 + r] = yp[r];
      }
    }
    __syncthreads();
  } // s

  // ---- tail: blend/write for the final step (pm synced by last barrier) ----
  if (wave == 0 && lane < 16) {
    float y = pm[0][lane] + pm[1][lane] + b2v;
    float pd = (nsteps == 1) ? y : fmaf(y, 1.0f - alpha, prevp * (alpha * 0.5f));
    out[(long)(b0g + lane) * nsteps + (nsteps - 1)] = pd;
  }
}

extern "C" void kernel_launch(void* const* d_in, const int* in_sizes, int n_in,
                              void* d_out, int out_size, void* d_ws, size_t ws_size,
                              hipStream_t stream) {
  (void)in_sizes; (void)n_in; (void)out_size; (void)d_ws; (void)ws_size;
  lstm_forecast<<<NBLK, NTHR, 0, stream>>>(
      (const float*)d_in[0],
      (const float*)d_in[1],  (const float*)d_in[2],
      (const float*)d_in[3],  (const float*)d_in[4],
      (const float*)d_in[5],  (const float*)d_in[6],
      (const float*)d_in[7],  (const float*)d_in[8],
      (const float*)d_in[9],  (const float*)d_in[10],
      (const float*)d_in[11], (const float*)d_in[12],
      (const float*)d_in[13], (const int*)d_in[14],
      (float*)d_out);
}

// Round 19
// 552.508 us; speedup vs baseline: 1.0214x; 1.0214x over previous
//
#include <hip/hip_runtime.h>

// AutoregressiveForecaster R19 = R16 verbatim (best verified: 553us).
// 2-layer LSTM(H=64) + MLP head, 20 steps, 24-window, B=8192.
//
//  - 512 blocks x 256 threads (4 waves), one 16-batch M-tile per block,
//    2 blocks/CU, pipelined L1(t)+L0(t+1), 1 barrier/iter, fused-7 gates,
//    log2e-prescaled weights (2x g-gate) in VGPRs.
//  - Phase stagger (odd blocks ~1400 ticks) decorrelates the two co-resident
//    blocks' barrier drains; setprio(1) on the serial gatestep chain (R16:
//    597->553, prediction matched).
//  - Structural ledger: waves/SIMD capped at 2 by batch/16=512 tiles x 4
//    waves (R2/R7/R8/R11/R14/R15 all measured worse); trans diet falsified
//    (R13); interval folds null/negative (R12/R18). Issue floor ~400us;
//    VALUBusy 72% of wall = issue efficiency at this latency structure.

typedef _Float16 f16x8 __attribute__((ext_vector_type(8)));
typedef float f32x4 __attribute__((ext_vector_type(4)));

#define NBLK 512
#define NTHR 256
#define SRB  144   // h row stride bytes

__device__ __forceinline__ float rcp_(float x) { return __builtin_amdgcn_rcpf(x); }
__device__ __forceinline__ float exp2_(float x) { return __builtin_amdgcn_exp2f(x); }
__device__ __forceinline__ f32x4 mfma16(uint4 a, uint4 b, f32x4 c) {
  return __builtin_amdgcn_mfma_f32_16x16x32_f16(
      __builtin_bit_cast(f16x8, a), __builtin_bit_cast(f16x8, b), c, 0, 0, 0);
}
__device__ __forceinline__ uint4 pack8s(const float* p, float s) {
  union { uint4 u; _Float16 h[8]; } r;
  #pragma unroll
  for (int i = 0; i < 8; ++i) r.h[i] = (_Float16)(p[i] * s);
  return r.u;
}
// fused LSTM gate update; pre-activations pre-scaled by log2e (2x for g-gate).
__device__ __forceinline__ float gatestep(float aI, float aF, float aG, float aO,
                                          float& cst) {
  float xx = exp2_(-aI), xf = exp2_(-aF), yy = exp2_(-aG), xo = exp2_(-aO);
  float P = (1.0f + xx) * (1.0f + yy);
  float Q = 1.0f + xf;
  float N = fmaf(cst, P, (1.0f - yy) * Q);   // c*P + (1-yy)*Q
  float cv = N * rcp_(P * Q);
  cst = cv;
  float z = exp2_(-2.88539008178f * cv);
  return (1.0f - z) * rcp_((1.0f + xo) * (1.0f + z));
}

__global__ __launch_bounds__(NTHR, 2) void lstm_forecast(
    const float* __restrict__ x,
    const float* __restrict__ Wih0, const float* __restrict__ Whh0,
    const float* __restrict__ bih0, const float* __restrict__ bhh0,
    const float* __restrict__ Wih1, const float* __restrict__ Whh1,
    const float* __restrict__ bih1, const float* __restrict__ bhh1,
    const float* __restrict__ W1,   const float* __restrict__ b1,
    const float* __restrict__ W2,   const float* __restrict__ b2,
    const float* __restrict__ damping, const int* __restrict__ stepsPtr,
    float* __restrict__ out)
{
  __shared__ __align__(16) char h1s[2][16 * SRB];
  __shared__ __align__(16) char h2s[2][16 * SRB];
  __shared__ __align__(16) float win[24 * 16];
  __shared__ __align__(16) float pm[2][16];

  const int tid  = threadIdx.x;
  const int wave = tid >> 6;
  const int lane = tid & 63;
  const int cc   = lane & 15;
  const int hi   = lane >> 4;
  const int b0g  = blockIdx.x * 16;
  const float L2E = 1.44269504089f;

  // ---- weight B-fragments into VGPRs (pre-scaled; gt: 0=i,1=f,2=g,3=o) ----
  uint4 wB0[4][2], wB1[4][2], wB2[4][2];
  float bias0v[4], wih0v[4];
  f32x4 bi1[4];
  #pragma unroll
  for (int gt = 0; gt < 4; ++gt) {
    float sc = (gt == 2) ? 2.0f * L2E : L2E;
    int row = (wave + 4 * gt) * 16 + cc;
    #pragma unroll
    for (int f = 0; f < 2; ++f) {
      int col = f * 32 + hi * 8;
      wB0[gt][f] = pack8s(Whh0 + row * 64 + col, sc);
      wB1[gt][f] = pack8s(Wih1 + row * 64 + col, sc);
      wB2[gt][f] = pack8s(Whh1 + row * 64 + col, sc);
    }
    bias0v[gt] = (bih0[row] + bhh0[row]) * sc;
    wih0v[gt]  = Wih0[row] * sc;
    float b1c  = (bih1[row] + bhh1[row]) * sc;
    #pragma unroll
    for (int r = 0; r < 4; ++r) bi1[gt][r] = b1c;
  }
  // MLP fragments (waves 0,1 use them; 2,3 load duplicates harmlessly)
  uint4 wM[2];
  {
    int row = (wave & 1) * 16 + cc;
    wM[0] = pack8s(W1 + row * 64 + hi * 8, 1.0f);
    wM[1] = pack8s(W1 + row * 64 + 32 + hi * 8, 1.0f);
  }
  const float w2v  = W2[(wave & 1) * 16 + cc];
  const float b1vv = b1[(wave & 1) * 16 + cc];
  const float alpha  = rcp_(1.0f + exp2_(-L2E * damping[0]));
  const int   nsteps = stepsPtr[0];
  const float b2v    = b2[0];

  // window init: win[t*16+b] = x[(b0g+b)*24 + t]
  for (int e = tid; e < 384; e += NTHR) {
    int b = e & 15, t = e >> 4;
    win[t * 16 + b] = x[(b0g + b) * 24 + t];
  }
  __syncthreads();

  // ---- one-time phase stagger: odd blocks delay ~1400 device cycles so the
  // two blocks sharing a CU hit their barriers out of phase. Output-neutral.
  if (blockIdx.x & 1) {
    unsigned long long t0 = __builtin_amdgcn_s_memtime();
    while (__builtin_amdgcn_s_memtime() - t0 < 1400ull) { }
  }

  const int offA = cc * SRB + hi * 16;           // A-frag byte offset
  const int offS = (wave * 16 + cc) * 2;         // elementwise store offset
  float prevp = 0.0f;

  for (int s = 0; s < nsteps; ++s) {
    float c1[4] = {0, 0, 0, 0}, c2s[4] = {0, 0, 0, 0};

    // ---- prologue: L0(0) elementwise only (h1(-1)=0) -> h1s[0] ----
    {
      float4 xw = *(const float4*)&win[(s % 24) * 16 + hi * 4];
      float xa[4] = {xw.x, xw.y, xw.z, xw.w};
      #pragma unroll
      for (int r = 0; r < 4; ++r) {
        float hv = gatestep(fmaf(xa[r], wih0v[0], bias0v[0]),
                            fmaf(xa[r], wih0v[1], bias0v[1]),
                            fmaf(xa[r], wih0v[2], bias0v[2]),
                            fmaf(xa[r], wih0v[3], bias0v[3]), c1[r]);
        *(_Float16*)(h1s[0] + (hi * 4 + r) * SRB + offS) = (_Float16)hv;
      }
    }
    __syncthreads();
    uint4 a1lo = *(const uint4*)(h1s[0] + offA);
    uint4 a1hi = *(const uint4*)(h1s[0] + offA + 64);
    uint4 a2lo = make_uint4(0, 0, 0, 0), a2hi = make_uint4(0, 0, 0, 0);

    // ---- main pipelined loop: iter t computes L1(t) and L0(t+1) ----
    for (int t = 0; t < 23; ++t) {
      int pb = (t + 1) & 1;
      int ph = s + t + 1; if (ph >= 24) ph -= 24;
      float4 xw = *(const float4*)&win[ph * 16 + hi * 4];
      float xa[4] = {xw.x, xw.y, xw.z, xw.w};

      f32x4 acc1[4], acc0[4];
      #pragma unroll
      for (int gt = 0; gt < 4; ++gt) {
        f32x4 tv = mfma16(a1lo, wB1[gt][0], bi1[gt]);
        tv = mfma16(a1hi, wB1[gt][1], tv);
        tv = mfma16(a2lo, wB2[gt][0], tv);
        acc1[gt] = mfma16(a2hi, wB2[gt][1], tv);
      }
      #pragma unroll
      for (int gt = 0; gt < 4; ++gt) {
        f32x4 ai;
        #pragma unroll
        for (int r = 0; r < 4; ++r) ai[r] = fmaf(xa[r], wih0v[gt], bias0v[gt]);
        f32x4 tv = mfma16(a1lo, wB0[gt][0], ai);
        acc0[gt] = mfma16(a1hi, wB0[gt][1], tv);
      }

      // serial gatestep region: boost priority so the co-resident (staggered)
      // block's bulk work yields issue slots to this latency chain.
      __builtin_amdgcn_s_setprio(1);
      char* h2d = h2s[pb];
      char* h1d = h1s[pb];
      #pragma unroll
      for (int r = 0; r < 4; ++r) {
        float hv = gatestep(acc1[0][r], acc1[1][r], acc1[2][r], acc1[3][r], c2s[r]);
        *(_Float16*)(h2d + (hi * 4 + r) * SRB + offS) = (_Float16)hv;
      }
      #pragma unroll
      for (int r = 0; r < 4; ++r) {
        float hv = gatestep(acc0[0][r], acc0[1][r], acc0[2][r], acc0[3][r], c1[r]);
        *(_Float16*)(h1d + (hi * 4 + r) * SRB + offS) = (_Float16)hv;
      }
      __builtin_amdgcn_s_setprio(0);
      __syncthreads();
      a1lo = *(const uint4*)(h1s[pb] + offA);
      a1hi = *(const uint4*)(h1s[pb] + offA + 64);
      a2lo = *(const uint4*)(h2s[pb] + offA);
      a2hi = *(const uint4*)(h2s[pb] + offA + 64);
    } // t

    // ---- epilogue: L1(23) -> h2s[0] ----
    {
      f32x4 acc1[4];
      #pragma unroll
      for (int gt = 0; gt < 4; ++gt) {
        f32x4 tv = mfma16(a1lo, wB1[gt][0], bi1[gt]);
        tv = mfma16(a1hi, wB1[gt][1], tv);
        tv = mfma16(a2lo, wB2[gt][0], tv);
        acc1[gt] = mfma16(a2hi, wB2[gt][1], tv);
      }
      __builtin_amdgcn_s_setprio(1);
      #pragma unroll
      for (int r = 0; r < 4; ++r) {
        float cv = c2s[r];
        float hv = gatestep(acc1[0][r], acc1[1][r], acc1[2][r], acc1[3][r], cv);
        *(_Float16*)(h2s[0] + (hi * 4 + r) * SRB + offS) = (_Float16)hv;
      }
      __builtin_amdgcn_s_setprio(0);
    }
    __syncthreads();

    // ---- MLP head on h2(23) (waves 0,1) ----
    if (wave < 2) {
      uint4 hflo = *(const uint4*)(h2s[0] + offA);
      uint4 hfhi = *(const uint4*)(h2s[0] + offA + 64);
      f32x4 am;
      #pragma unroll
      for (int r = 0; r < 4; ++r) am[r] = b1vv;
      am = mfma16(hflo, wM[0], am);
      am = mfma16(hfhi, wM[1], am);
      float yp[4];
      #pragma unroll
      for (int r = 0; r < 4; ++r) yp[r] = fmaxf(am[r], 0.0f) * w2v;
      #pragma unroll
      for (int mask = 1; mask <= 8; mask <<= 1) {
        #pragma unroll
        for (int r = 0; r < 4; ++r) yp[r] += __shfl_xor(yp[r], mask);
      }
      if (cc == 0) {
        #pragma unroll
        for (int r = 0; r < 4; ++r) pm[wave][hi * 4 + r] = yp[r];
      }
    }
    __syncthreads();

    if (wave == 0 && lane < 16) {
      float y = pm[0][lane] + pm[1][lane] + b2v;
      float pd = (s == 0) ? y : fmaf(y, 1.0f - alpha, prevp * (alpha * 0.5f));
      prevp = pd;
      win[(s % 24) * 16 + lane] = pd;
      out[(long)(b0g + lane) * nsteps + s] = pd;
    }
    __syncthreads();
  } // s
}

extern "C" void kernel_launch(void* const* d_in, const int* in_sizes, int n_in,
                              void* d_out, int out_size, void* d_ws, size_t ws_size,
                              hipStream_t stream) {
  (void)in_sizes; (void)n_in; (void)out_size; (void)d_ws; (void)ws_size;
  lstm_forecast<<<NBLK, NTHR, 0, stream>>>(
      (const float*)d_in[0],
      (const float*)d_in[1],  (const float*)d_in[2],
      (const float*)d_in[3],  (const float*)d_in[4],
      (const float*)d_in[5],  (const float*)d_in[6],
      (const float*)d_in[7],  (const float*)d_in[8],
      (const float*)d_in[9],  (const float*)d_in[10],
      (const float*)d_in[11], (const float*)d_in[12],
      (const float*)d_in[13], (const int*)d_in[14],
      (float*)d_out);
}